// Round 2
// baseline (2602.386 us; speedup 1.0000x reference)
//
#include <hip/hip_runtime.h>

// DTW accumulated-cost, output = last column. N=65536 rows (input), K=512 cols (kernel).
// Anti-diagonal recurrence, 4 waves (one per SIMD), j = 128*w + 2*lane + slot,
// skewed-chunk barrier pipeline passing band-boundary E values through LDS rings.
//
// R4: force the x prefetch to actually happen. R3's VGPR_Count=32 proved the
// compiler sank the "prefetched" loads to their use sites (live range ~2 regs),
// putting a ~900cy cross-XCD L3/HBM latency inside every 16-iter block
// (4 stalls/superstep ~= the measured 5082cy/superstep). Changes:
//  - x loads: ONE asm volatile block of 32 global_load_dwordx2 per chunk
//    (8B-aligned; odd lanes make 16B alignment impossible). Issued at superstep
//    start for chunk c+1, consumed next superstep -> full-superstep latency cover.
//    asm volatile + "memory"-clobbered barriers make this placement non-negotiable.
//  - manual s_waitcnt vmcnt(0) at superstep start (prior VMEM is >=1 superstep
//    old => free) + sched_barrier(0) after it (rule #18: register-only ITERs
//    must not hoist above the wait).
//  - per-wave chunk loop: skew = w intro barriers + 3-w drain barriers
//    (1035 s_barriers per wave, same rendezvous count as R3's superstep loop),
//    so the A/B x-buffers have static names in both phases (rule #20).
//  - barrier stays LDS-only: "s_waitcnt lgkmcnt(0); s_barrier".

#define K_LEN 512
#define N_LEN 65536
#define PAD_L 512
#define PAD_R 1024
#define XPAD_TOTAL (PAD_L + N_LEN + PAD_R) // 67072 floats = 268288 B of d_ws
#define BIGX 1e20f
#define NCHUNK 1032                        // 1032*64 = 66048 >= N+K-1 = 66047 diagonals
#define RING 256                           // ring entries per boundary buffer (4 chunks)

typedef float f32x2 __attribute__((ext_vector_type(2)));

__global__ void dtw_pad_kernel(const float* __restrict__ x, float* __restrict__ xpad) {
    int i = blockIdx.x * blockDim.x + threadIdx.x;
    if (i < XPAD_TOTAL) {
        int j = i - PAD_L;
        xpad[i] = (j >= 0 && j < N_LEN) ? x[j] : BIGX;
    }
}

// lane l <- lane l-1 of src; lane 0 <- old[0]        (wave_shr:1, bound_ctrl=0)
__device__ __forceinline__ float dpp_wave_shr1(float oldv, float src) {
    return __int_as_float(__builtin_amdgcn_update_dpp(
        __float_as_int(oldv), __float_as_int(src), 0x138, 0xF, 0xF, false));
}
// lane l <- lane l+1 of src; lane 63 <- old[63]      (wave_shl:1, bound_ctrl=0)
__device__ __forceinline__ float dpp_wave_shl1(float oldv, float src) {
    return __int_as_float(__builtin_amdgcn_update_dpp(
        __float_as_int(oldv), __float_as_int(src), 0x130, 0xF, 0xF, false));
}

#define BARRIER() asm volatile("s_waitcnt lgkmcnt(0)\n\ts_barrier" ::: "memory")

struct XBuf { f32x2 v[32]; };

// 64 floats (one chunk's x stream for this lane) in one non-movable asm block.
// p is 8B-aligned for every lane (PAD_L - j0 is even, chunk offsets are even).
__device__ __forceinline__ void load_chunk(XBuf& b, const float* p) {
    asm volatile(
        "global_load_dwordx2 %0,  %[ad], off\n\t"
        "global_load_dwordx2 %1,  %[ad], off offset:8\n\t"
        "global_load_dwordx2 %2,  %[ad], off offset:16\n\t"
        "global_load_dwordx2 %3,  %[ad], off offset:24\n\t"
        "global_load_dwordx2 %4,  %[ad], off offset:32\n\t"
        "global_load_dwordx2 %5,  %[ad], off offset:40\n\t"
        "global_load_dwordx2 %6,  %[ad], off offset:48\n\t"
        "global_load_dwordx2 %7,  %[ad], off offset:56\n\t"
        "global_load_dwordx2 %8,  %[ad], off offset:64\n\t"
        "global_load_dwordx2 %9,  %[ad], off offset:72\n\t"
        "global_load_dwordx2 %10, %[ad], off offset:80\n\t"
        "global_load_dwordx2 %11, %[ad], off offset:88\n\t"
        "global_load_dwordx2 %12, %[ad], off offset:96\n\t"
        "global_load_dwordx2 %13, %[ad], off offset:104\n\t"
        "global_load_dwordx2 %14, %[ad], off offset:112\n\t"
        "global_load_dwordx2 %15, %[ad], off offset:120\n\t"
        "global_load_dwordx2 %16, %[ad], off offset:128\n\t"
        "global_load_dwordx2 %17, %[ad], off offset:136\n\t"
        "global_load_dwordx2 %18, %[ad], off offset:144\n\t"
        "global_load_dwordx2 %19, %[ad], off offset:152\n\t"
        "global_load_dwordx2 %20, %[ad], off offset:160\n\t"
        "global_load_dwordx2 %21, %[ad], off offset:168\n\t"
        "global_load_dwordx2 %22, %[ad], off offset:176\n\t"
        "global_load_dwordx2 %23, %[ad], off offset:184\n\t"
        "global_load_dwordx2 %24, %[ad], off offset:192\n\t"
        "global_load_dwordx2 %25, %[ad], off offset:200\n\t"
        "global_load_dwordx2 %26, %[ad], off offset:208\n\t"
        "global_load_dwordx2 %27, %[ad], off offset:216\n\t"
        "global_load_dwordx2 %28, %[ad], off offset:224\n\t"
        "global_load_dwordx2 %29, %[ad], off offset:232\n\t"
        "global_load_dwordx2 %30, %[ad], off offset:240\n\t"
        "global_load_dwordx2 %31, %[ad], off offset:248"
        : "=v"(b.v[0]),  "=v"(b.v[1]),  "=v"(b.v[2]),  "=v"(b.v[3]),
          "=v"(b.v[4]),  "=v"(b.v[5]),  "=v"(b.v[6]),  "=v"(b.v[7]),
          "=v"(b.v[8]),  "=v"(b.v[9]),  "=v"(b.v[10]), "=v"(b.v[11]),
          "=v"(b.v[12]), "=v"(b.v[13]), "=v"(b.v[14]), "=v"(b.v[15]),
          "=v"(b.v[16]), "=v"(b.v[17]), "=v"(b.v[18]), "=v"(b.v[19]),
          "=v"(b.v[20]), "=v"(b.v[21]), "=v"(b.v[22]), "=v"(b.v[23]),
          "=v"(b.v[24]), "=v"(b.v[25]), "=v"(b.v[26]), "=v"(b.v[27]),
          "=v"(b.v[28]), "=v"(b.v[29]), "=v"(b.v[30]), "=v"(b.v[31])
        : [ad] "v"(p)
        : "memory");
}

template <bool LAST>
__device__ __forceinline__ void compute_chunk(int c, const XBuf& b, float binv,
                                              float k0, float k1,
                                              float& A0, float& A0p, float& A1, float& E1,
                                              float& xp, int lane,
                                              float* __restrict__ ldsOut,
                                              float* __restrict__ out) {
    const int t0 = c * 64;
    const int rb = (c & 3) * 64;
    float keepreg = 0.0f; // fully overwritten by 64 inserts

    auto ITER = [&](float xf) {
        // slot0 shifted E: lane l <- lane l-1's E1; lane 0 <- binv[0] (= boundary r)
        const float esh0 = dpp_wave_shr1(binv, E1);
        binv = dpp_wave_shl1(binv, binv); // advance: lane0 <- next boundary value
        const float t0v = k0 - xf;
        const float na0 = __builtin_fmaf(t0v, t0v, fminf(A0, esh0));
        const float t1v = k1 - xp;
        const float m1  = fminf(A0p, fminf(A1, A0)); // = min(A1, E0_prev)
        const float na1 = __builtin_fmaf(t1v, t1v, m1);
        const float ne1 = fminf(na1, A1);
        // collect lane63's value (wave3: column-511 output); after 64 shifts
        // lane r holds the iter-r value
        keepreg = dpp_wave_shl1(LAST ? na1 : ne1, keepreg);
        A0p = A0; A0 = na0; A1 = na1; E1 = ne1; xp = xf;
    };

#pragma unroll
    for (int q = 0; q < 32; ++q) { ITER(b.v[q].x); ITER(b.v[q].y); }

    if (!LAST) {
        ldsOut[rb + lane] = keepreg;            // single ds_write_b32, conflict-free
    } else {
        const int oi = t0 + lane - (K_LEN - 1); // coalesced chunk output
        if (oi >= 0 && oi < N_LEN) out[oi] = keepreg;
    }
}

__global__ __launch_bounds__(256, 1) void dtw_main(const float* __restrict__ xpad,
                                                   const float* __restrict__ kern,
                                                   float* __restrict__ out) {
    __shared__ float lds[4 * RING]; // buf[w]=w*RING for waves 0..2; INIT at 3*RING (wave0's in)
    const float INFV = __builtin_inff();
    const int tid  = threadIdx.x;
    const int w    = __builtin_amdgcn_readfirstlane(tid) >> 6; // wave id, uniform SGPR
    const int lane = tid & 63;

    // LDS init: all INF; INIT[255] = 0.0 is the DP seed ac[-1][-1]=0 (wave0, chunk0, r=0)
    for (int i = tid; i < 4 * RING; i += 256)
        lds[i] = (i == 4 * RING - 1) ? 0.0f : INFV;
    __syncthreads();

    const int j0 = w * 128 + 2 * lane;      // slot-0 column; slot-1 = j0+1
    const float k0 = kern[j0];
    const float k1 = kern[j0 + 1];

    const float* xl = xpad + (PAD_L - j0);  // fresh (slot-0) x at diagonal t is xl[t]
    float xp = xl[-1];                      // slot-1 x entering t=0

    float* ldsOut      = lds + w * RING;    // wave3 never writes (LAST path)
    const float* ldsIn = (w == 0) ? (lds + 3 * RING) : (lds + (w - 1) * RING);

    float A0 = INFV, A0p = INFV, A1 = INFV, E1 = INFV;

    XBuf bA, bB;
    load_chunk(bA, xl);                     // chunk 0's x, issued before the skew intro

    for (int b = 0; b < w; ++b) BARRIER();  // skew intro: wave w starts chunk 0 at superstep w

    for (int cc = 0; cc < NCHUNK; cc += 2) {
        { // ---- phase A: compute chunk cc from bA; prefetch cc+1 -> bB ----
            asm volatile("s_waitcnt vmcnt(0)" ::: "memory"); // bA's loads (1 superstep old)
            __builtin_amdgcn_sched_barrier(0);               // rule #18: no hoist above wait
            load_chunk(bB, xl + (cc + 1) * 64);              // issue-early prefetch
            __builtin_amdgcn_sched_barrier(0);
            const int c = cc;
            const float binv = ldsIn[((c & 3) * 64 + lane - 1) & (RING - 1)];
            if (w == 3)
                compute_chunk<true >(c, bA, binv, k0, k1, A0, A0p, A1, E1, xp, lane, ldsOut, out);
            else
                compute_chunk<false>(c, bA, binv, k0, k1, A0, A0p, A1, E1, xp, lane, ldsOut, out);
            if (cc == 0 && tid == 0) lds[4 * RING - 1] = INFV; // retire seed (same-wave DS order)
            BARRIER();
        }
        { // ---- phase B: compute chunk cc+1 from bB; prefetch cc+2 -> bA ----
            asm volatile("s_waitcnt vmcnt(0)" ::: "memory");
            __builtin_amdgcn_sched_barrier(0);
            load_chunk(bA, xl + (cc + 2) * 64);  // cc+2==NCHUNK at the end: in-bounds junk
            __builtin_amdgcn_sched_barrier(0);
            const int c = cc + 1;
            const float binv = ldsIn[((c & 3) * 64 + lane - 1) & (RING - 1)];
            if (w == 3)
                compute_chunk<true >(c, bB, binv, k0, k1, A0, A0p, A1, E1, xp, lane, ldsOut, out);
            else
                compute_chunk<false>(c, bB, binv, k0, k1, A0, A0p, A1, E1, xp, lane, ldsOut, out);
            BARRIER();
        }
    }

    for (int b = 0; b < 3 - w; ++b) BARRIER(); // drain: every wave executes 1035 barriers
}

extern "C" void kernel_launch(void* const* d_in, const int* in_sizes, int n_in,
                              void* d_out, int out_size, void* d_ws, size_t ws_size,
                              hipStream_t stream) {
    const float* x = (const float*)d_in[0];   // input, 65536 fp32
    const float* k = (const float*)d_in[1];   // kernel, 512 fp32
    float* xpad = (float*)d_ws;               // needs 268288 B of scratch
    float* out  = (float*)d_out;              // 65536 fp32
    dtw_pad_kernel<<<(XPAD_TOTAL + 255) / 256, 256, 0, stream>>>(x, xpad);
    dtw_main<<<1, 256, 0, stream>>>(xpad, k, out);
}

// Round 3
// 2328.257 us; speedup vs baseline: 1.1177x; 1.1177x over previous
//
#include <hip/hip_runtime.h>

// DTW accumulated-cost, output = last column. N=65536 rows (input), K=512 cols (kernel).
// Anti-diagonal recurrence, 4 waves (one per SIMD), j = 128*w + 2*lane + slot,
// skewed-chunk barrier pipeline passing band-boundary E values through LDS rings.
//
// R5: counted-vmcnt sub-block pipeline (T3/T4) sized to FIT REGISTERS.
//  - R3 (VGPR=32): compiler sank loads -> ~4 raw ~350cy L3 latencies/superstep.
//  - R4 (VGPR=104): forced 2x64-VGPR double buffer -> allocator spilled it to
//    scratch (128+state > 104) -> R3's stalls + scratch traffic = 2590us.
//  - R5: 4 static sub-buffers of 8 f32x2 (64 VGPR total). Per 16-iter sub-block:
//    issue next+2 sub-block's 8 global_load_dwordx2 (asm volatile), then
//    s_waitcnt vmcnt(16) (counted, never 0: 2 batches always in flight, loads
//    live across barriers) + sched_barrier(0) (rule #18), then 16 register-only
//    iters. Wave3's single in-flight output store only forces one extra retire
//    of an already-old load (harmless).
//  - merged DPP FIFO: boundary-consume (lane0) and keep-collect (lane63 insert)
//    share ONE register shifting wave_shl:1 -> 2 DPP/iter (was 3).

#define K_LEN 512
#define N_LEN 65536
#define PAD_L 512
#define PAD_R 1024
#define XPAD_TOTAL (PAD_L + N_LEN + PAD_R) // 67072 floats = 268288 B of d_ws
#define BIGX 1e20f
#define NCHUNK 1032                        // 1032*64 = 66048 >= N+K-1 = 66047 diagonals
#define RING 256                           // ring entries per boundary buffer (4 chunks)

typedef float f32x2 __attribute__((ext_vector_type(2)));

__global__ void dtw_pad_kernel(const float* __restrict__ x, float* __restrict__ xpad) {
    int i = blockIdx.x * blockDim.x + threadIdx.x;
    if (i < XPAD_TOTAL) {
        int j = i - PAD_L;
        xpad[i] = (j >= 0 && j < N_LEN) ? x[j] : BIGX;
    }
}

// lane l <- lane l-1 of src; lane 0 <- old[0]        (wave_shr:1, bound_ctrl=0)
__device__ __forceinline__ float dpp_wave_shr1(float oldv, float src) {
    return __int_as_float(__builtin_amdgcn_update_dpp(
        __float_as_int(oldv), __float_as_int(src), 0x138, 0xF, 0xF, false));
}
// lane l <- lane l+1 of src; lane 63 <- old[63]      (wave_shl:1, bound_ctrl=0)
__device__ __forceinline__ float dpp_wave_shl1(float oldv, float src) {
    return __int_as_float(__builtin_amdgcn_update_dpp(
        __float_as_int(oldv), __float_as_int(src), 0x130, 0xF, 0xF, false));
}

#define BARRIER() asm volatile("s_waitcnt lgkmcnt(0)\n\ts_barrier" ::: "memory")
// counted wait: all but the newest 16 VMEM ops retired (= the sub-block needed now),
// then a hard scheduling fence so register-only iters cannot hoist above it (rule #18)
#define WAITV16() do { asm volatile("s_waitcnt vmcnt(16)" ::: "memory"); \
                       __builtin_amdgcn_sched_barrier(0); } while (0)

struct XB { f32x2 v[8]; }; // one 16-iter sub-block of the per-lane x stream

// 16 floats in one non-movable asm block (p is 8B-aligned: PAD_L - j0 even).
__device__ __forceinline__ void load_sb(XB& b, const float* p) {
    asm volatile(
        "global_load_dwordx2 %0, %[ad], off\n\t"
        "global_load_dwordx2 %1, %[ad], off offset:8\n\t"
        "global_load_dwordx2 %2, %[ad], off offset:16\n\t"
        "global_load_dwordx2 %3, %[ad], off offset:24\n\t"
        "global_load_dwordx2 %4, %[ad], off offset:32\n\t"
        "global_load_dwordx2 %5, %[ad], off offset:40\n\t"
        "global_load_dwordx2 %6, %[ad], off offset:48\n\t"
        "global_load_dwordx2 %7, %[ad], off offset:56"
        : "=v"(b.v[0]), "=v"(b.v[1]), "=v"(b.v[2]), "=v"(b.v[3]),
          "=v"(b.v[4]), "=v"(b.v[5]), "=v"(b.v[6]), "=v"(b.v[7])
        : [ad] "v"(p)
        : "memory");
}

template <bool LAST>
__device__ __forceinline__ void run_loop(const float* __restrict__ xl,
                                         const float* __restrict__ ldsIn,
                                         float* __restrict__ ldsOut,
                                         float* __restrict__ lds,
                                         float k0, float k1, int lane, int tid,
                                         float* __restrict__ out) {
    const float INFV = __builtin_inff();
    float A0 = INFV, A0p = INFV, A1 = INFV, E1 = INFV;
    float xp = xl[-1]; // slot-1 x entering t=0

    XB b0, b1, b2, b3;
    // bk: merged DPP FIFO. At iter r of a chunk, lane0 holds boundary value r;
    // each iter consumes lane0 (via dpp old) and inserts the keep value at lane63.
    // After 64 iters lane r holds the iter-r keep value (publish/store it).
    float bk;

    auto ITER = [&](float xf) {
        const float esh0 = dpp_wave_shr1(bk, E1); // lane0 <- bk[0]; l>=1 <- E1[l-1]
        const float t0v = k0 - xf;
        const float na0 = __builtin_fmaf(t0v, t0v, fminf(A0, esh0));
        const float t1v = k1 - xp;
        const float m1  = fminf(A0p, fminf(A1, A0)); // = min(A1, E0_prev)
        const float na1 = __builtin_fmaf(t1v, t1v, m1);
        const float ne1 = fminf(na1, A1);
        bk = dpp_wave_shl1(LAST ? na1 : ne1, bk); // shift FIFO, insert keep at 63
        A0p = A0; A0 = na0; A1 = na1; E1 = ne1; xp = xf;
    };
    auto COMPUTE = [&](const XB& b) {
#pragma unroll
        for (int q = 0; q < 8; ++q) { ITER(b.v[q].x); ITER(b.v[q].y); }
    };

    load_sb(b0, xl);            // chunk0 sub-block 0
    load_sb(b1, xl + 16);       // chunk0 sub-block 1

    // (skew-intro barriers are executed by the caller before this function)

    for (int c = 0; c < NCHUNK; ++c) {
        const int t0 = c * 64;
        const int rb = (c & 3) << 6;
        bk = ldsIn[(rb + lane - 1) & (RING - 1)]; // fresh boundary FIFO (ds_read)

        load_sb(b2, xl + t0 + 32); WAITV16(); COMPUTE(b0); // pos0
        load_sb(b3, xl + t0 + 48); WAITV16(); COMPUTE(b1); // pos1
        load_sb(b0, xl + t0 + 64); WAITV16(); COMPUTE(b2); // pos2 (next chunk sb0)
        load_sb(b1, xl + t0 + 80); WAITV16(); COMPUTE(b3); // pos3 (next chunk sb1)

        if (!LAST) {
            ldsOut[rb + lane] = bk;               // single ds_write_b32, conflict-free
        } else {
            const int oi = t0 + lane - (K_LEN - 1);
            if (oi >= 0 && oi < N_LEN) out[oi] = bk; // coalesced chunk output
        }
        if (c == 0 && tid == 0) lds[4 * RING - 1] = INFV; // retire seed before ring wraps
        BARRIER(); // LDS-only drain: loads (and wave3's store) stay in flight
    }
}

__global__ __launch_bounds__(256, 1) void dtw_main(const float* __restrict__ xpad,
                                                   const float* __restrict__ kern,
                                                   float* __restrict__ out) {
    __shared__ float lds[4 * RING]; // buf[w]=w*RING for waves 0..2; INIT at 3*RING (wave0's in)
    const float INFV = __builtin_inff();
    const int tid  = threadIdx.x;
    const int w    = __builtin_amdgcn_readfirstlane(tid) >> 6; // wave id, uniform SGPR
    const int lane = tid & 63;

    // LDS init: all INF; INIT[255] = 0.0 is the DP seed ac[-1][-1]=0 (wave0, chunk0, r=0)
    for (int i = tid; i < 4 * RING; i += 256)
        lds[i] = (i == 4 * RING - 1) ? 0.0f : INFV;
    __syncthreads();

    const int j0 = w * 128 + 2 * lane;      // slot-0 column; slot-1 = j0+1
    const float k0 = kern[j0];
    const float k1 = kern[j0 + 1];

    const float* xl = xpad + (PAD_L - j0);  // fresh (slot-0) x at diagonal t is xl[t]

    float* ldsOut      = lds + w * RING;    // wave3 never writes (LAST path)
    const float* ldsIn = (w == 0) ? (lds + 3 * RING) : (lds + (w - 1) * RING);

    for (int b = 0; b < w; ++b) BARRIER();  // skew intro: wave w starts chunk 0 at superstep w

    if (w == 3)
        run_loop<true >(xl, ldsIn, ldsOut, lds, k0, k1, lane, tid, out);
    else
        run_loop<false>(xl, ldsIn, ldsOut, lds, k0, k1, lane, tid, out);

    for (int b = 0; b < 3 - w; ++b) BARRIER(); // drain: every wave executes 1035 barriers
}

extern "C" void kernel_launch(void* const* d_in, const int* in_sizes, int n_in,
                              void* d_out, int out_size, void* d_ws, size_t ws_size,
                              hipStream_t stream) {
    const float* x = (const float*)d_in[0];   // input, 65536 fp32
    const float* k = (const float*)d_in[1];   // kernel, 512 fp32
    float* xpad = (float*)d_ws;               // needs 268288 B of scratch
    float* out  = (float*)d_out;              // 65536 fp32
    dtw_pad_kernel<<<(XPAD_TOTAL + 255) / 256, 256, 0, stream>>>(x, xpad);
    dtw_main<<<1, 256, 0, stream>>>(xpad, k, out);
}